// Round 3
// baseline (556.848 us; speedup 1.0000x reference)
//
#include <hip/hip_runtime.h>
#include <hip/hip_bf16.h>
#include <stdint.h>

// GAT-style attention layer, B=4 N=4096 Din=256 Dout=128, fp32 in/out.
// Pipeline (R10: 3 kernels, was 5):
//  k1 : h = x@W (fp32), store hT (fp16, [b][d][n]) + Wh1/Wh2 = h@a (fp32)
//  k2 : ONE coalesced pass over adj: S_j (atomicAdd) + transposed bitmask
//       m32[b][jw][i]; 16-deep load batches
//  k3 : out = gelu(P @ h), fp16 MFMA.
//       R8: double-buffered DMA pipeline — per-wave 2x8KB LDS, counted
//       s_waitcnt vmcnt(8) + one-chunk-ahead register prefetch.
//       R9a: k25 folded in — loads S, v_rcp in-kernel (8 VALU/chunk, hidden
//       under the exp_gelu phase; rcp err << fp16-h quantization floor).
//       R10: k4b folded via MANUAL grid barrier (R9's cooperative launch
//       broke under graph capture — absmax 1.0). Plain launch; arrival
//       counter with ACQ_REL/ACQUIRE AGENT-scope atomics. Co-residency is
//       structural: 64KB LDS -> exactly 2 blocks/CU, grid 512 = 2x256 CU,
//       launch_bounds(256,2) caps VGPR<=256 -> no capacity deadlock.
//       Bounded spin (~0.8s) so a model error fails the bench, never hangs.
//       Saves k25 + k4b launches + k4b's 16.8 MB out read+rewrite.
//
// R7 lesson: __launch_bounds__(512,4) capped VGPRs at 128 (borderline ->
// possible spill); occupancy past 2 waves/SIMD buys nothing because each
// wave is ~83% VALU-dense. Stick to 256-thr / cap-256.

#define NN   4096
#define BB   4
#define DIN  256
#define DOUT 128
#define NBLK (BB * (NN / 32))   // 512 blocks in k3

typedef unsigned short u16;
typedef _Float16 f16x8 __attribute__((ext_vector_type(8)));
typedef __attribute__((ext_vector_type(4))) float f32x4;

__device__ __forceinline__ u16 f2h_bits(float f) {
  _Float16 h = (_Float16)f;          // v_cvt_f16_f32, RNE
  union { _Float16 h; u16 u; } v; v.h = h;
  return v.u;
}

// Abramowitz-Stegun 7.1.26, |err| < 1.5e-7
__device__ __forceinline__ float erf_f(float x) {
  float ax = __builtin_fabsf(x);
  float t  = __builtin_amdgcn_rcpf(__builtin_fmaf(0.3275911f, ax, 1.0f));
  float p  = __builtin_fmaf(1.061405429f, t, -1.453152027f);
  p = __builtin_fmaf(p, t, 1.421413741f);
  p = __builtin_fmaf(p, t, -0.284496736f);
  p = __builtin_fmaf(p, t, 0.254829592f);
  p = p * t;
  float e  = __expf(-ax * ax);
  float er = __builtin_fmaf(-p, e, 1.0f);
  return copysignf(er, x);
}

__device__ __forceinline__ float gelu_f(float z) {
  float hz = 0.5f * z;
  return __builtin_fmaf(hz, erf_f(z * 0.70710678118654752f), hz);
}

__device__ __forceinline__ float exp_gelu(float z) { return __expf(gelu_f(z)); }

// ---------------- k1: h = x@W, Wh1/Wh2, hT(fp16) ----------------
__global__ __launch_bounds__(256, 2) void k1_proj(
    const float* __restrict__ x, const float* __restrict__ weight,
    const float* __restrict__ a, u16* __restrict__ hT,
    float* __restrict__ Wh1, float* __restrict__ Wh2)
{
  __shared__ float xs[32 * 256];     // 32 KB
  __shared__ float T[128 * 33];      // padded transpose buffer (16.9 KB)
  __shared__ float P2a[8 * 32], P2b[8 * 32];

  const int b = blockIdx.y, n0 = blockIdx.x * 32;
  const int tid = threadIdx.x;

  const float4* xsrc = (const float4*)(x + ((size_t)b * NN + n0) * DIN);
  float4* xd = (float4*)xs;
#pragma unroll
  for (int v = 0; v < 8; ++v) xd[tid + v * 256] = xsrc[tid + v * 256];
  __syncthreads();

  const int dg = tid & 31, rg = tid >> 5;
  float acc[4][4] = {};
  const float4* W4 = (const float4*)weight;
#pragma unroll 4
  for (int k = 0; k < 256; ++k) {
    float4 wr = W4[k * 32 + dg];
#pragma unroll
    for (int rr = 0; rr < 4; ++rr) {
      float xv = xs[(rg * 4 + rr) * 256 + k];
      acc[rr][0] = fmaf(xv, wr.x, acc[rr][0]);
      acc[rr][1] = fmaf(xv, wr.y, acc[rr][1]);
      acc[rr][2] = fmaf(xv, wr.z, acc[rr][2]);
      acc[rr][3] = fmaf(xv, wr.w, acc[rr][3]);
    }
  }
#pragma unroll
  for (int rr = 0; rr < 4; ++rr)
#pragma unroll
    for (int dd = 0; dd < 4; ++dd)
      T[(dg * 4 + dd) * 33 + rg * 4 + rr] = acc[rr][dd];
  __syncthreads();

  {
    const int d = tid & 127, half = tid >> 7;
    unsigned int uu[8];
#pragma unroll
    for (int p = 0; p < 8; ++p) {
      float f0 = T[d * 33 + half * 16 + p * 2];
      float f1 = T[d * 33 + half * 16 + p * 2 + 1];
      uu[p] = (unsigned int)f2h_bits(f0) | ((unsigned int)f2h_bits(f1) << 16);
    }
    u16* dst = hT + ((size_t)b * DOUT + d) * NN + n0 + half * 16;
    ((uint4*)dst)[0] = make_uint4(uu[0], uu[1], uu[2], uu[3]);
    ((uint4*)dst)[1] = make_uint4(uu[4], uu[5], uu[6], uu[7]);
  }
  {
    const int r = tid & 31, g8 = tid >> 5;
    float p1 = 0.f, p2 = 0.f;
#pragma unroll
    for (int q = 0; q < 16; ++q) {
      int d = g8 * 16 + q;
      float hv = T[d * 33 + r];
      p1 = fmaf(hv, a[d], p1);
      p2 = fmaf(hv, a[DOUT + d], p2);
    }
    P2a[g8 * 32 + r] = p1;
    P2b[g8 * 32 + r] = p2;
  }
  __syncthreads();
  if (tid < 32) {
    float s1 = 0.f, s2 = 0.f;
#pragma unroll
    for (int g8 = 0; g8 < 8; ++g8) { s1 += P2a[g8 * 32 + tid]; s2 += P2b[g8 * 32 + tid]; }
    Wh1[b * NN + n0 + tid] = s1;
    Wh2[b * NN + n0 + tid] = s2;
  }
}

// ---------------- k2: fused adj pass -> S_j + transposed bitmask ----------------
// grid (16 jt, 32 ic, BB) = 2048 blocks, block 256: thread = column
// j = jt*256+tid, 128 rows per thread. adj loads lane-consecutive 4 B
// (coalesced), batched 16-deep for outstanding-load depth. Per 64-row group:
// 64 ballots accumulated into per-lane u64, one coalesced store into
// transposed planes m32[b][jw][i].
__global__ __launch_bounds__(256) void k2_fused(
    const int* __restrict__ adj, const float* __restrict__ Wh1,
    const float* __restrict__ Wh2, float* __restrict__ S,
    unsigned int* __restrict__ m32)
{
  const int b = blockIdx.z, jt = blockIdx.x, ic = blockIdx.y;
  const int tid = threadIdx.x;
  const int j = jt * 256 + tid;
  const int lane = tid & 63;
  const int jg = jt * 4 + (tid >> 6);      // global 64-j group
  const int i0 = ic * 128;

  const float wh2 = Wh2[b * NN + j];
  const int* ap = adj + ((size_t)b * NN + i0) * NN + j;
  const float* w1p = Wh1 + b * NN + i0;
  unsigned int* mlo = m32 + ((size_t)b * 128 + jg * 2) * NN + i0;
  unsigned int* mhi = mlo + NN;

  float s = 0.f;
  for (int g = 0; g < 2; ++g) {            // 2 groups of 64 rows
    unsigned long long acc64 = 0ull;
#pragma unroll
    for (int gg = 0; gg < 4; ++gg) {       // 4 sub-batches of 16 rows
      int av[16]; float w1v[16];
#pragma unroll
      for (int k = 0; k < 16; ++k) {
        const int ii = g * 64 + gg * 16 + k;
        av[k]  = ap[(size_t)ii * NN];
        w1v[k] = w1p[ii];                  // block-uniform -> scalar load
      }
#pragma unroll
      for (int k = 0; k < 16; ++k) {
        const unsigned long long bal = __ballot(av[k] > 0);
        if (lane == gg * 16 + k) acc64 = bal;   // cndmask keep
        const float E = exp_gelu(w1v[k] + wh2);
        s += (av[k] > 0) ? E : 0.f;
      }
    }
    mlo[g * 64 + lane] = (unsigned int)acc64;          // coalesced 256 B
    mhi[g * 64 + lane] = (unsigned int)(acc64 >> 32);  // coalesced 256 B
  }
  atomicAdd(&S[b * NN + j], s);
}

// ---------------- k3: out = gelu(P @ h) via fp16 MFMA + fused norm + bias ----------------
// Plain launch, grid (NN/32, BB) = 512 blocks, block 256 = 4 waves.
// 64 KB LDS -> exactly 2 blocks/CU -> all 512 blocks co-resident on 256 CUs
// (manual grid barrier is capacity-safe; bounded spin as failsafe).
// Wave w owns j in [w*1024, +1024) (4-way K-split), private 2x8 KB LDS
// double-buffer. No __syncthreads in the K-loop.
// Pipeline per chunk c (steady state):
//   (1) reg-prefetch chunk c+1 operands (6 VMEM) + v_rcp of S (k25 folded)
//   (2) lgkmcnt(0) WAR guard, issue 8 global_load_lds for chunk c+1 -> buf[cur^1]
//   (3) VALU: build A-operands for chunk c from regs prefetched last iter
//   (4) s_waitcnt vmcnt(8): chunk c's DMA done, chunk c+1's 8 DMAs STAY in
//       flight (counted wait, never vmcnt(0) in the loop)
//   (5) ds_read buf[cur] + 16 MFMA
// Last iteration re-issues chunk 31 (clamped) so the count stays uniform.
// Epilogue: K-split reduce, gelu -> REGISTERS, norm2 atomics, manual grid
// barrier, AGENT-scope norm2 load (XCD-L2 staleness guard, G16), fused
// scale+bias single out write.
__global__ __launch_bounds__(256, 2) void k3_attn(
    const unsigned int* __restrict__ m32, const float* __restrict__ Wh1,
    const float* __restrict__ Wh2, const float* __restrict__ S,
    const u16* __restrict__ hT, const float* __restrict__ bias,
    float* __restrict__ out, float* __restrict__ norm2,
    unsigned int* __restrict__ bar)
{
  __shared__ __align__(16) u16 buf[4][2][4096];   // 4 waves x 2 x 8 KB = 64 KB

  const int b = blockIdx.y;
  const int i0 = blockIdx.x * 32;
  const int tid = threadIdx.x;
  const int w = tid >> 6, lane = tid & 63;
  const int m = lane & 15, quad = lane >> 4;

  const float w1a = Wh1[b * NN + i0 + m];
  const float w1b = Wh1[b * NN + i0 + 16 + m];
  const unsigned int* mbase = m32 + (size_t)b * 128 * NN;
  const u16* hTb = hT + (size_t)b * DOUT * NN;
  // staging: lane l covers row (l>>2)+inst*16, j-offset (l&3)*8 -> LDS u16 ofs l*8
  const u16* srcbase = hTb + (size_t)(lane >> 2) * NN + (lane & 3) * 8;

  f32x4 acc0[8], acc1[8];
#pragma unroll
  for (int t = 0; t < 8; ++t) {
    acc0[t] = (f32x4){0.f, 0.f, 0.f, 0.f};
    acc1[t] = (f32x4){0.f, 0.f, 0.f, 0.f};
  }

  const int jbase = w * 1024;

  // ---- prologue: chunk-0 operand regs + chunk-0 DMA into buf[w][0] ----
  unsigned int Ma, Mb;
  float4 w2a, w2b, sva, svb;
  {
    const int j0 = jbase;
    const int jw = j0 >> 5;
    Ma = mbase[(size_t)jw * NN + i0 + m];
    Mb = mbase[(size_t)jw * NN + i0 + 16 + m];
    const int jq = j0 + quad * 8;
    const float4* wp = (const float4*)(Wh2 + b * NN + jq);
    w2a = wp[0]; w2b = wp[1];
    const float4* sp = (const float4*)(S + b * NN + jq);
    sva = sp[0]; svb = sp[1];
    sva.x = __builtin_amdgcn_rcpf(sva.x); sva.y = __builtin_amdgcn_rcpf(sva.y);
    sva.z = __builtin_amdgcn_rcpf(sva.z); sva.w = __builtin_amdgcn_rcpf(sva.w);
    svb.x = __builtin_amdgcn_rcpf(svb.x); svb.y = __builtin_amdgcn_rcpf(svb.y);
    svb.z = __builtin_amdgcn_rcpf(svb.z); svb.w = __builtin_amdgcn_rcpf(svb.w);
  }
#pragma unroll
  for (int inst = 0; inst < 8; ++inst) {
    const u16* g = srcbase + (size_t)inst * 16 * NN + jbase;
    __builtin_amdgcn_global_load_lds(
        (const __attribute__((address_space(1))) void*)g,
        (__attribute__((address_space(3))) void*)&buf[w][0][inst * 512],
        16, 0, 0);
  }

  for (int c = 0; c < 32; ++c) {
    const int cur = c & 1;
    const int cn = (c < 31) ? c + 1 : 31;      // clamp keeps vmcnt count uniform
    const int j0n = jbase + cn * 32;

    // (1) register prefetch for chunk cn (6 VMEM ops) + in-kernel rcp
    const int jwn = j0n >> 5;
    const unsigned int Ma_n = mbase[(size_t)jwn * NN + i0 + m];
    const unsigned int Mb_n = mbase[(size_t)jwn * NN + i0 + 16 + m];
    const int jqn = j0n + quad * 8;
    const float4* wpn = (const float4*)(Wh2 + b * NN + jqn);
    const float4 w2a_n = wpn[0], w2b_n = wpn[1];
    const float4* spn = (const float4*)(S + b * NN + jqn);
    float4 sva_n = spn[0], svb_n = spn[1];
    sva_n.x = __builtin_amdgcn_rcpf(sva_n.x); sva_n.y = __builtin_amdgcn_rcpf(sva_n.y);
    sva_n.z = __builtin_amdgcn_rcpf(sva_n.z); sva_n.w = __builtin_amdgcn_rcpf(sva_n.w);
    svb_n.x = __builtin_amdgcn_rcpf(svb_n.x); svb_n.y = __builtin_amdgcn_rcpf(svb_n.y);
    svb_n.z = __builtin_amdgcn_rcpf(svb_n.z); svb_n.w = __builtin_amdgcn_rcpf(svb_n.w);

    // (2) WAR guard: ds_reads of chunk c-1 (which used buf[cur^1]) must be
    // complete before the DMA overwrites it; then issue chunk cn's 8 DMAs.
    __builtin_amdgcn_s_waitcnt(0xC07F);   // lgkmcnt(0) only
    __builtin_amdgcn_sched_barrier(0);    // pin DMAs below the guard
#pragma unroll
    for (int inst = 0; inst < 8; ++inst) {
      const u16* g = srcbase + (size_t)inst * 16 * NN + j0n;
      __builtin_amdgcn_global_load_lds(
          (const __attribute__((address_space(1))) void*)g,
          (__attribute__((address_space(3))) void*)&buf[w][cur ^ 1][inst * 512],
          16, 0, 0);
    }

    // (3) A-operand VALU for chunk c (regs prefetched one iteration ago)
    const unsigned int mba = (Ma >> (quad * 8)) & 0xFFu;
    const unsigned int mbb = (Mb >> (quad * 8)) & 0xFFu;

    f16x8 ah_a, ah_b;
    // row-tile a (rows i0..i0+15)
    ah_a[0] = (_Float16)((mba & 1u)   ? exp_gelu(w1a + w2a.x) * sva.x : 0.f);
    ah_a[1] = (_Float16)((mba & 2u)   ? exp_gelu(w1a + w2a.y) * sva.y : 0.f);
    ah_a[2] = (_Float16)((mba & 4u)   ? exp_gelu(w1a + w2a.z) * sva.z : 0.f);
    ah_a[3] = (_Float16)((mba & 8u)   ? exp_gelu(w1a + w2a.w) * sva.w : 0.f);
    ah_a[4] = (_Float16)((mba & 16u)  ? exp_gelu(w1a + w2b.x) * svb.x : 0.f);
    ah_a[5] = (_Float16)((mba & 32u)  ? exp_gelu(w1a + w2b.y) * svb.y : 0.f);
    ah_a[6] = (_Float16)((mba & 64u)  ? exp_gelu(w1a + w2b.z) * svb.z : 0.f);
    ah_a[7] = (_Float16)((mba & 128u) ? exp_gelu(w1a + w2b.w) * svb.w : 0.f);
    // row-tile b (rows i0+16..i0+31)
    ah_b[0] = (_Float16)((mbb & 1u)   ? exp_gelu(w1b + w2a.x) * sva.x : 0.f);
    ah_b[1] = (_Float16)((mbb & 2u)   ? exp_gelu(w1b + w2a.y) * sva.y : 0.f);
    ah_b[2] = (_Float16)((mbb & 4u)   ? exp_gelu(w1b + w2a.z) * sva.z : 0.f);
    ah_b[3] = (_Float16)((mbb & 8u)   ? exp_gelu(w1b + w2a.w) * sva.w : 0.f);
    ah_b[4] = (_Float16)((mbb & 16u)  ? exp_gelu(w1b + w2b.x) * svb.x : 0.f);
    ah_b[5] = (_Float16)((mbb & 32u)  ? exp_gelu(w1b + w2b.y) * svb.y : 0.f);
    ah_b[6] = (_Float16)((mbb & 64u)  ? exp_gelu(w1b + w2b.z) * svb.z : 0.f);
    ah_b[7] = (_Float16)((mbb & 128u) ? exp_gelu(w1b + w2b.w) * svb.w : 0.f);

    // (4) counted wait: chunk c's DMA done; chunk cn's 8 DMAs stay in flight
    __builtin_amdgcn_sched_barrier(0);
    __builtin_amdgcn_s_waitcnt(0x0F78);   // vmcnt(8) only
    __builtin_amdgcn_sched_barrier(0);    // pin ds_reads below the wait

    // (5) LDS fragments + MFMA for chunk c
#pragma unroll
    for (int t = 0; t < 8; ++t) {
      f16x8 bf = *(const f16x8*)&buf[w][cur][(t * 16 + m) * 32 + quad * 8];
      acc0[t] = __builtin_amdgcn_mfma_f32_16x16x32_f16(ah_a, bf, acc0[t], 0, 0, 0);
      acc1[t] = __builtin_amdgcn_mfma_f32_16x16x32_f16(ah_b, bf, acc1[t], 0, 0, 0);
    }

    // (6) rotate operand regs
    Ma = Ma_n; Mb = Mb_n;
    w2a = w2a_n; w2b = w2b_n; sva = sva_n; svb = svb_n;
  }

  // 4-way K-split reduce (red = 4 x 2048 fp32 = 32 KB, first half of buf),
  // two passes. The leading __syncthreads drains vmcnt(0) (compiler-emitted
  // full drain before s_barrier), so the trailing redundant DMA cannot land
  // after the reduction writes.
  // Fused epilogue: gelu -> registers, per-block norm2 atomics.
  float* red = (float*)&buf[0][0][0];
  float p2[2] = {0.f, 0.f};
  float gv[2][2][4];                       // [rt][tt][r], all static indices
#pragma unroll
  for (int rt = 0; rt < 2; ++rt) {
    __syncthreads();
#pragma unroll
    for (int t = 0; t < 8; ++t)
#pragma unroll
      for (int r = 0; r < 4; ++r)
        red[w * 2048 + (t * 4 + r) * 64 + lane] = rt ? acc1[t][r] : acc0[t][r];
    __syncthreads();
    // wave w finalizes d-tiles t = 2w, 2w+1 (C layout: row=quad*4+r, col=t*16+m)
#pragma unroll
    for (int tt = 0; tt < 2; ++tt) {
      const int t = w * 2 + tt;
#pragma unroll
      for (int r = 0; r < 4; ++r) {
        const int o = (t * 4 + r) * 64 + lane;
        float v = red[o] + red[2048 + o] + red[4096 + o] + red[6144 + o];
        float g = gelu_f(v);
        gv[rt][tt][r] = g;
        p2[tt] = fmaf(g, g, p2[tt]);
      }
    }
  }
  // cross-quad reduce (lanes m, m+16, m+32, m+48 share d), one atomic per d
#pragma unroll
  for (int tt = 0; tt < 2; ++tt) {
    float ps = p2[tt];
    ps += __shfl_xor(ps, 16);
    ps += __shfl_xor(ps, 32);
    if (quad == 0)
      atomicAdd(&norm2[b * DOUT + (w * 2 + tt) * 16 + m], ps);
  }

  // ---- manual grid barrier (capacity-safe: 512 blocks, 2/CU x 256 CU) ----
  // __syncthreads drains the norm2 atomics to the coherence point; tid 0's
  // RELEASE increment publishes them; ACQUIRE spin-load observes all 512
  // arrivals => all norm2 contributions. Bounded spin: never hang the bench.
  __syncthreads();
  if (tid == 0) {
    __hip_atomic_fetch_add(bar, 1u, __ATOMIC_ACQ_REL, __HIP_MEMORY_SCOPE_AGENT);
    unsigned int spins = 0;
    while (__hip_atomic_load(bar, __ATOMIC_ACQUIRE, __HIP_MEMORY_SCOPE_AGENT)
           < (unsigned int)NBLK) {
      __builtin_amdgcn_s_sleep(8);
      if (++spins > 4000000u) break;   // ~0.8 s failsafe
    }
  }
  __syncthreads();

  // ---- fused L2-normalize + bias + single out write ----
  float scb[2], bsv[2];
#pragma unroll
  for (int tt = 0; tt < 2; ++tt) {
    const int d = (w * 2 + tt) * 16 + m;
    // AGENT-scope load: a plain load could hit a stale per-XCD L2/L1 line.
    float n2 = __hip_atomic_load(&norm2[b * DOUT + d], __ATOMIC_RELAXED,
                                 __HIP_MEMORY_SCOPE_AGENT);
    scb[tt] = 1.0f / fmaxf(sqrtf(n2), 1e-12f);
    bsv[tt] = bias[d];
  }
#pragma unroll
  for (int rt = 0; rt < 2; ++rt)
#pragma unroll
    for (int tt = 0; tt < 2; ++tt)
#pragma unroll
      for (int r = 0; r < 4; ++r)
        out[((size_t)b * NN + i0 + rt * 16 + quad * 4 + r) * DOUT +
            (w * 2 + tt) * 16 + m] = fmaf(gv[rt][tt][r], scb[tt], bsv[tt]);
}

extern "C" void kernel_launch(void* const* d_in, const int* in_sizes, int n_in,
                              void* d_out, int out_size, void* d_ws, size_t ws_size,
                              hipStream_t stream)
{
  const float* x      = (const float*)d_in[0];
  const int*   adj    = (const int*)d_in[1];
  const float* weight = (const float*)d_in[2];
  const float* a      = (const float*)d_in[3];
  const float* bias   = (const float*)d_in[4];
  float* out = (float*)d_out;

  // workspace layout (all 16B aligned), ~12.3 MB total
  char* ws = (char*)d_ws;
  u16*   hT     = (u16*)ws;                                    // 4 MB
  float* Wh1    = (float*)(ws + (size_t)4 * 1024 * 1024);      // 64 KB
  float* Wh2    = Wh1 + BB * NN;                               // 64 KB
  float* S      = Wh2 + BB * NN;                               // 64 KB
  float* Sinv   = S + BB * NN;                                 // 64 KB (unused, keeps layout)
  unsigned int* m32 = (unsigned int*)(Sinv + BB * NN);         // 8 MB, [b][128][4096]
  float* norm2  = (float*)((char*)m32 + (size_t)BB * 128 * NN * 4);  // 2 KB
  unsigned int* bar = (unsigned int*)(norm2 + BB * DOUT);      // 4 B (+pad)

  hipMemsetAsync(S, 0, (size_t)BB * NN * sizeof(float), stream);
  // one memset covers norm2 (2 KB) + barrier counter (contiguous)
  hipMemsetAsync(norm2, 0, (size_t)BB * DOUT * sizeof(float) + 64, stream);

  k1_proj<<<dim3(NN / 32, BB), 256, 0, stream>>>(x, weight, a, hT, Wh1, Wh2);
  k2_fused<<<dim3(16, 32, BB), 256, 0, stream>>>(adj, Wh1, Wh2, S, m32);
  k3_attn<<<dim3(NN / 32, BB), 256, 0, stream>>>(m32, Wh1, Wh2, S, hT, bias,
                                                 out, norm2, bar);
}

// Round 4
// 485.013 us; speedup vs baseline: 1.1481x; 1.1481x over previous
//
#include <hip/hip_runtime.h>
#include <hip/hip_bf16.h>
#include <stdint.h>

// GAT-style attention layer, B=4 N=4096 Din=256 Dout=128, fp32 in/out.
// Pipeline (R11: 4 kernels):
//  k1 : h = x@W (fp32), store hT (fp16, [b][d][n]) + Wh1/Wh2 = h@a (fp32)
//  k2 : ONE coalesced pass over adj: S_j (atomicAdd) + transposed bitmask
//       m32[b][jw][i]; 16-deep load batches
//  k3 : out = gelu(P @ h), fp16 MFMA.
//       R8: double-buffered DMA pipeline — per-wave 2x8KB LDS, counted
//       s_waitcnt vmcnt(8) + one-chunk-ahead register prefetch.
//       R9a: k25 folded — loads S, v_rcp in-kernel (proven in R10).
//  k4b: L2-normalize over i + bias (separate kernel).
//
// R10 lesson: grid-barrier fusion of k4b = +55 µs (slowest-block tail +
// spin + register pressure across the barrier) — retire-independently wins.
// R11: exp_gelu for attention logits switched from erf-based (~18 VALU,
// 3 trans) to tanh-approx fused with the outer exp (~10 VALU, 3 trans):
//   exp(gelu(z)) ~= exp(z*(1-1/(E+1))), E = exp(1.5957691*z*(1+0.044715 z^2))
// max gelu err ~3e-4 -> P err ~6e-4 relative -> far below fp16-h floor.
// Used identically in k2 (S) and k3 (P) so softmax stays consistent; the
// epilogue's OUTPUT gelu stays erf-exact (2M evals, directly compared).
//
// R7 lesson: stick to 256-thr / cap-256 (512,4 spilled).

#define NN   4096
#define BB   4
#define DIN  256
#define DOUT 128

typedef unsigned short u16;
typedef _Float16 f16x8 __attribute__((ext_vector_type(8)));
typedef __attribute__((ext_vector_type(4))) float f32x4;

__device__ __forceinline__ u16 f2h_bits(float f) {
  _Float16 h = (_Float16)f;          // v_cvt_f16_f32, RNE
  union { _Float16 h; u16 u; } v; v.h = h;
  return v.u;
}

// Abramowitz-Stegun 7.1.26, |err| < 1.5e-7 (used for the OUTPUT gelu only)
__device__ __forceinline__ float erf_f(float x) {
  float ax = __builtin_fabsf(x);
  float t  = __builtin_amdgcn_rcpf(__builtin_fmaf(0.3275911f, ax, 1.0f));
  float p  = __builtin_fmaf(1.061405429f, t, -1.453152027f);
  p = __builtin_fmaf(p, t, 1.421413741f);
  p = __builtin_fmaf(p, t, -0.284496736f);
  p = __builtin_fmaf(p, t, 0.254829592f);
  p = p * t;
  float e  = __expf(-ax * ax);
  float er = __builtin_fmaf(-p, e, 1.0f);
  return copysignf(er, x);
}

__device__ __forceinline__ float gelu_f(float z) {
  float hz = 0.5f * z;
  return __builtin_fmaf(hz, erf_f(z * 0.70710678118654752f), hz);
}

// exp(gelu(z)) for the attention logits: tanh-approx gelu fused with the
// outer exp. gelu_tanh(z) = 0.5z(1+tanh(0.7978846(z+0.044715 z^3)))
//                        = z*(1 - 1/(E+1)),  E = exp(2*0.7978846*w)
// Tails exact: E->inf => e^z (rcp(inf)=0); E->0 => 1. 10 VALU ops, 3 trans.
__device__ __forceinline__ float exp_gelu(float z) {
  float w = z * __builtin_fmaf(0.044715f, z * z, 1.0f);
  float E = __expf(1.5957691f * w);
  float r = __builtin_amdgcn_rcpf(E + 1.0f);
  return __expf(__builtin_fmaf(-z, r, z));   // exp(z*(1-r))
}

// ---------------- k1: h = x@W, Wh1/Wh2, hT(fp16) ----------------
__global__ __launch_bounds__(256, 2) void k1_proj(
    const float* __restrict__ x, const float* __restrict__ weight,
    const float* __restrict__ a, u16* __restrict__ hT,
    float* __restrict__ Wh1, float* __restrict__ Wh2)
{
  __shared__ float xs[32 * 256];     // 32 KB
  __shared__ float T[128 * 33];      // padded transpose buffer (16.9 KB)
  __shared__ float P2a[8 * 32], P2b[8 * 32];

  const int b = blockIdx.y, n0 = blockIdx.x * 32;
  const int tid = threadIdx.x;

  const float4* xsrc = (const float4*)(x + ((size_t)b * NN + n0) * DIN);
  float4* xd = (float4*)xs;
#pragma unroll
  for (int v = 0; v < 8; ++v) xd[tid + v * 256] = xsrc[tid + v * 256];
  __syncthreads();

  const int dg = tid & 31, rg = tid >> 5;
  float acc[4][4] = {};
  const float4* W4 = (const float4*)weight;
#pragma unroll 4
  for (int k = 0; k < 256; ++k) {
    float4 wr = W4[k * 32 + dg];
#pragma unroll
    for (int rr = 0; rr < 4; ++rr) {
      float xv = xs[(rg * 4 + rr) * 256 + k];
      acc[rr][0] = fmaf(xv, wr.x, acc[rr][0]);
      acc[rr][1] = fmaf(xv, wr.y, acc[rr][1]);
      acc[rr][2] = fmaf(xv, wr.z, acc[rr][2]);
      acc[rr][3] = fmaf(xv, wr.w, acc[rr][3]);
    }
  }
#pragma unroll
  for (int rr = 0; rr < 4; ++rr)
#pragma unroll
    for (int dd = 0; dd < 4; ++dd)
      T[(dg * 4 + dd) * 33 + rg * 4 + rr] = acc[rr][dd];
  __syncthreads();

  {
    const int d = tid & 127, half = tid >> 7;
    unsigned int uu[8];
#pragma unroll
    for (int p = 0; p < 8; ++p) {
      float f0 = T[d * 33 + half * 16 + p * 2];
      float f1 = T[d * 33 + half * 16 + p * 2 + 1];
      uu[p] = (unsigned int)f2h_bits(f0) | ((unsigned int)f2h_bits(f1) << 16);
    }
    u16* dst = hT + ((size_t)b * DOUT + d) * NN + n0 + half * 16;
    ((uint4*)dst)[0] = make_uint4(uu[0], uu[1], uu[2], uu[3]);
    ((uint4*)dst)[1] = make_uint4(uu[4], uu[5], uu[6], uu[7]);
  }
  {
    const int r = tid & 31, g8 = tid >> 5;
    float p1 = 0.f, p2 = 0.f;
#pragma unroll
    for (int q = 0; q < 16; ++q) {
      int d = g8 * 16 + q;
      float hv = T[d * 33 + r];
      p1 = fmaf(hv, a[d], p1);
      p2 = fmaf(hv, a[DOUT + d], p2);
    }
    P2a[g8 * 32 + r] = p1;
    P2b[g8 * 32 + r] = p2;
  }
  __syncthreads();
  if (tid < 32) {
    float s1 = 0.f, s2 = 0.f;
#pragma unroll
    for (int g8 = 0; g8 < 8; ++g8) { s1 += P2a[g8 * 32 + tid]; s2 += P2b[g8 * 32 + tid]; }
    Wh1[b * NN + n0 + tid] = s1;
    Wh2[b * NN + n0 + tid] = s2;
  }
}

// ---------------- k2: fused adj pass -> S_j + transposed bitmask ----------------
// grid (16 jt, 32 ic, BB) = 2048 blocks, block 256: thread = column
// j = jt*256+tid, 128 rows per thread. adj loads lane-consecutive 4 B
// (coalesced), batched 16-deep for outstanding-load depth. Per 64-row group:
// 64 ballots accumulated into per-lane u64, one coalesced store into
// transposed planes m32[b][jw][i].
__global__ __launch_bounds__(256) void k2_fused(
    const int* __restrict__ adj, const float* __restrict__ Wh1,
    const float* __restrict__ Wh2, float* __restrict__ S,
    unsigned int* __restrict__ m32)
{
  const int b = blockIdx.z, jt = blockIdx.x, ic = blockIdx.y;
  const int tid = threadIdx.x;
  const int j = jt * 256 + tid;
  const int lane = tid & 63;
  const int jg = jt * 4 + (tid >> 6);      // global 64-j group
  const int i0 = ic * 128;

  const float wh2 = Wh2[b * NN + j];
  const int* ap = adj + ((size_t)b * NN + i0) * NN + j;
  const float* w1p = Wh1 + b * NN + i0;
  unsigned int* mlo = m32 + ((size_t)b * 128 + jg * 2) * NN + i0;
  unsigned int* mhi = mlo + NN;

  float s = 0.f;
  for (int g = 0; g < 2; ++g) {            // 2 groups of 64 rows
    unsigned long long acc64 = 0ull;
#pragma unroll
    for (int gg = 0; gg < 4; ++gg) {       // 4 sub-batches of 16 rows
      int av[16]; float w1v[16];
#pragma unroll
      for (int k = 0; k < 16; ++k) {
        const int ii = g * 64 + gg * 16 + k;
        av[k]  = ap[(size_t)ii * NN];
        w1v[k] = w1p[ii];                  // block-uniform -> scalar load
      }
#pragma unroll
      for (int k = 0; k < 16; ++k) {
        const unsigned long long bal = __ballot(av[k] > 0);
        if (lane == gg * 16 + k) acc64 = bal;   // cndmask keep
        const float E = exp_gelu(w1v[k] + wh2);
        s += (av[k] > 0) ? E : 0.f;
      }
    }
    mlo[g * 64 + lane] = (unsigned int)acc64;          // coalesced 256 B
    mhi[g * 64 + lane] = (unsigned int)(acc64 >> 32);  // coalesced 256 B
  }
  atomicAdd(&S[b * NN + j], s);
}

// ---------------- k3: out = gelu(P @ h) via fp16 MFMA + fused norm2 ----------------
// grid (NN/32, BB) = 512 blocks, block 256 = 4 waves; block covers 32 rows.
// Wave w owns j in [w*1024, +1024) (4-way K-split), private 2x8 KB LDS
// double-buffer. No __syncthreads in the K-loop.
// Pipeline per chunk c (steady state):
//   (1) reg-prefetch chunk c+1 operands (6 VMEM) + v_rcp of S (k25 folded)
//   (2) lgkmcnt(0) WAR guard, issue 8 global_load_lds for chunk c+1 -> buf[cur^1]
//   (3) VALU: build A-operands for chunk c from regs prefetched last iter
//   (4) s_waitcnt vmcnt(8): chunk c's DMA done, chunk c+1's 8 DMAs STAY in
//       flight (counted wait, never vmcnt(0) in the loop)
//   (5) ds_read buf[cur] + 16 MFMA
// Last iteration re-issues chunk 31 (clamped) so the count stays uniform.
// Epilogue: K-split reduce, gelu, write d_out, per-block norm2 atomics.
__global__ __launch_bounds__(256, 2) void k3_attn(
    const unsigned int* __restrict__ m32, const float* __restrict__ Wh1,
    const float* __restrict__ Wh2, const float* __restrict__ S,
    const u16* __restrict__ hT, float* __restrict__ out,
    float* __restrict__ norm2)
{
  __shared__ __align__(16) u16 buf[4][2][4096];   // 4 waves x 2 x 8 KB = 64 KB

  const int b = blockIdx.y;
  const int i0 = blockIdx.x * 32;
  const int tid = threadIdx.x;
  const int w = tid >> 6, lane = tid & 63;
  const int m = lane & 15, quad = lane >> 4;

  const float w1a = Wh1[b * NN + i0 + m];
  const float w1b = Wh1[b * NN + i0 + 16 + m];
  const unsigned int* mbase = m32 + (size_t)b * 128 * NN;
  const u16* hTb = hT + (size_t)b * DOUT * NN;
  // staging: lane l covers row (l>>2)+inst*16, j-offset (l&3)*8 -> LDS u16 ofs l*8
  const u16* srcbase = hTb + (size_t)(lane >> 2) * NN + (lane & 3) * 8;

  f32x4 acc0[8], acc1[8];
#pragma unroll
  for (int t = 0; t < 8; ++t) {
    acc0[t] = (f32x4){0.f, 0.f, 0.f, 0.f};
    acc1[t] = (f32x4){0.f, 0.f, 0.f, 0.f};
  }

  const int jbase = w * 1024;

  // ---- prologue: chunk-0 operand regs + chunk-0 DMA into buf[w][0] ----
  unsigned int Ma, Mb;
  float4 w2a, w2b, sva, svb;
  {
    const int j0 = jbase;
    const int jw = j0 >> 5;
    Ma = mbase[(size_t)jw * NN + i0 + m];
    Mb = mbase[(size_t)jw * NN + i0 + 16 + m];
    const int jq = j0 + quad * 8;
    const float4* wp = (const float4*)(Wh2 + b * NN + jq);
    w2a = wp[0]; w2b = wp[1];
    const float4* sp = (const float4*)(S + b * NN + jq);
    sva = sp[0]; svb = sp[1];
    sva.x = __builtin_amdgcn_rcpf(sva.x); sva.y = __builtin_amdgcn_rcpf(sva.y);
    sva.z = __builtin_amdgcn_rcpf(sva.z); sva.w = __builtin_amdgcn_rcpf(sva.w);
    svb.x = __builtin_amdgcn_rcpf(svb.x); svb.y = __builtin_amdgcn_rcpf(svb.y);
    svb.z = __builtin_amdgcn_rcpf(svb.z); svb.w = __builtin_amdgcn_rcpf(svb.w);
  }
#pragma unroll
  for (int inst = 0; inst < 8; ++inst) {
    const u16* g = srcbase + (size_t)inst * 16 * NN + jbase;
    __builtin_amdgcn_global_load_lds(
        (const __attribute__((address_space(1))) void*)g,
        (__attribute__((address_space(3))) void*)&buf[w][0][inst * 512],
        16, 0, 0);
  }

  for (int c = 0; c < 32; ++c) {
    const int cur = c & 1;
    const int cn = (c < 31) ? c + 1 : 31;      // clamp keeps vmcnt count uniform
    const int j0n = jbase + cn * 32;

    // (1) register prefetch for chunk cn (6 VMEM ops) + in-kernel rcp
    const int jwn = j0n >> 5;
    const unsigned int Ma_n = mbase[(size_t)jwn * NN + i0 + m];
    const unsigned int Mb_n = mbase[(size_t)jwn * NN + i0 + 16 + m];
    const int jqn = j0n + quad * 8;
    const float4* wpn = (const float4*)(Wh2 + b * NN + jqn);
    const float4 w2a_n = wpn[0], w2b_n = wpn[1];
    const float4* spn = (const float4*)(S + b * NN + jqn);
    float4 sva_n = spn[0], svb_n = spn[1];
    sva_n.x = __builtin_amdgcn_rcpf(sva_n.x); sva_n.y = __builtin_amdgcn_rcpf(sva_n.y);
    sva_n.z = __builtin_amdgcn_rcpf(sva_n.z); sva_n.w = __builtin_amdgcn_rcpf(sva_n.w);
    svb_n.x = __builtin_amdgcn_rcpf(svb_n.x); svb_n.y = __builtin_amdgcn_rcpf(svb_n.y);
    svb_n.z = __builtin_amdgcn_rcpf(svb_n.z); svb_n.w = __builtin_amdgcn_rcpf(svb_n.w);

    // (2) WAR guard: ds_reads of chunk c-1 (which used buf[cur^1]) must be
    // complete before the DMA overwrites it; then issue chunk cn's 8 DMAs.
    __builtin_amdgcn_s_waitcnt(0xC07F);   // lgkmcnt(0) only
    __builtin_amdgcn_sched_barrier(0);    // pin DMAs below the guard
#pragma unroll
    for (int inst = 0; inst < 8; ++inst) {
      const u16* g = srcbase + (size_t)inst * 16 * NN + j0n;
      __builtin_amdgcn_global_load_lds(
          (const __attribute__((address_space(1))) void*)g,
          (__attribute__((address_space(3))) void*)&buf[w][cur ^ 1][inst * 512],
          16, 0, 0);
    }

    // (3) A-operand VALU for chunk c (regs prefetched one iteration ago)
    const unsigned int mba = (Ma >> (quad * 8)) & 0xFFu;
    const unsigned int mbb = (Mb >> (quad * 8)) & 0xFFu;

    f16x8 ah_a, ah_b;
    // row-tile a (rows i0..i0+15)
    ah_a[0] = (_Float16)((mba & 1u)   ? exp_gelu(w1a + w2a.x) * sva.x : 0.f);
    ah_a[1] = (_Float16)((mba & 2u)   ? exp_gelu(w1a + w2a.y) * sva.y : 0.f);
    ah_a[2] = (_Float16)((mba & 4u)   ? exp_gelu(w1a + w2a.z) * sva.z : 0.f);
    ah_a[3] = (_Float16)((mba & 8u)   ? exp_gelu(w1a + w2a.w) * sva.w : 0.f);
    ah_a[4] = (_Float16)((mba & 16u)  ? exp_gelu(w1a + w2b.x) * svb.x : 0.f);
    ah_a[5] = (_Float16)((mba & 32u)  ? exp_gelu(w1a + w2b.y) * svb.y : 0.f);
    ah_a[6] = (_Float16)((mba & 64u)  ? exp_gelu(w1a + w2b.z) * svb.z : 0.f);
    ah_a[7] = (_Float16)((mba & 128u) ? exp_gelu(w1a + w2b.w) * svb.w : 0.f);
    // row-tile b (rows i0+16..i0+31)
    ah_b[0] = (_Float16)((mbb & 1u)   ? exp_gelu(w1b + w2a.x) * sva.x : 0.f);
    ah_b[1] = (_Float16)((mbb & 2u)   ? exp_gelu(w1b + w2a.y) * sva.y : 0.f);
    ah_b[2] = (_Float16)((mbb & 4u)   ? exp_gelu(w1b + w2a.z) * sva.z : 0.f);
    ah_b[3] = (_Float16)((mbb & 8u)   ? exp_gelu(w1b + w2a.w) * sva.w : 0.f);
    ah_b[4] = (_Float16)((mbb & 16u)  ? exp_gelu(w1b + w2b.x) * svb.x : 0.f);
    ah_b[5] = (_Float16)((mbb & 32u)  ? exp_gelu(w1b + w2b.y) * svb.y : 0.f);
    ah_b[6] = (_Float16)((mbb & 64u)  ? exp_gelu(w1b + w2b.z) * svb.z : 0.f);
    ah_b[7] = (_Float16)((mbb & 128u) ? exp_gelu(w1b + w2b.w) * svb.w : 0.f);

    // (4) counted wait: chunk c's DMA done; chunk cn's 8 DMAs stay in flight
    __builtin_amdgcn_sched_barrier(0);
    __builtin_amdgcn_s_waitcnt(0x0F78);   // vmcnt(8) only
    __builtin_amdgcn_sched_barrier(0);    // pin ds_reads below the wait

    // (5) LDS fragments + MFMA for chunk c
#pragma unroll
    for (int t = 0; t < 8; ++t) {
      f16x8 bf = *(const f16x8*)&buf[w][cur][(t * 16 + m) * 32 + quad * 8];
      acc0[t] = __builtin_amdgcn_mfma_f32_16x16x32_f16(ah_a, bf, acc0[t], 0, 0, 0);
      acc1[t] = __builtin_amdgcn_mfma_f32_16x16x32_f16(ah_b, bf, acc1[t], 0, 0, 0);
    }

    // (6) rotate operand regs
    Ma = Ma_n; Mb = Mb_n;
    w2a = w2a_n; w2b = w2b_n; sva = sva_n; svb = svb_n;
  }

  // 4-way K-split reduce (red = 4 x 2048 fp32 = 32 KB, first half of buf),
  // two passes. The leading __syncthreads drains vmcnt(0) (compiler-emitted
  // full drain before s_barrier), so the trailing redundant DMA cannot land
  // after the reduction writes.
  // Fused epilogue: gelu -> out, accumulate per-d sum of squares.
  float* red = (float*)&buf[0][0][0];
  float p2[2] = {0.f, 0.f};
#pragma unroll
  for (int rt = 0; rt < 2; ++rt) {
    __syncthreads();
#pragma unroll
    for (int t = 0; t < 8; ++t)
#pragma unroll
      for (int r = 0; r < 4; ++r)
        red[w * 2048 + (t * 4 + r) * 64 + lane] = rt ? acc1[t][r] : acc0[t][r];
    __syncthreads();
    // wave w finalizes d-tiles t = 2w, 2w+1 (C layout: row=quad*4+r, col=t*16+m)
#pragma unroll
    for (int tt = 0; tt < 2; ++tt) {
      const int t = w * 2 + tt;
#pragma unroll
      for (int r = 0; r < 4; ++r) {
        const int o = (t * 4 + r) * 64 + lane;
        float v = red[o] + red[2048 + o] + red[4096 + o] + red[6144 + o];
        float gv = gelu_f(v);
        out[((size_t)b * NN + i0 + rt * 16 + quad * 4 + r) * DOUT + t * 16 + m] = gv;
        p2[tt] = fmaf(gv, gv, p2[tt]);
      }
    }
  }
  // cross-quad reduce (lanes m, m+16, m+32, m+48 share d), one atomic per d
#pragma unroll
  for (int tt = 0; tt < 2; ++tt) {
    float ps = p2[tt];
    ps += __shfl_xor(ps, 16);
    ps += __shfl_xor(ps, 32);
    if (quad == 0)
      atomicAdd(&norm2[b * DOUT + (w * 2 + tt) * 16 + m], ps);
  }
}

// ---------------- k4b: scale by 1/max(||col||,1e-12) + bias ----------------
__global__ __launch_bounds__(256) void k4b_scale(
    float* __restrict__ out, const float* __restrict__ norm2,
    const float* __restrict__ bias)
{
  int id = blockIdx.x * 256 + threadIdx.x;
  int d = id & 127;
  int b = id >> 19;                        // N*DOUT = 2^19 per batch
  float nrm = sqrtf(norm2[b * DOUT + d]);
  float sc = 1.0f / fmaxf(nrm, 1e-12f);
  out[id] = fmaf(out[id], sc, bias[d]);
}

extern "C" void kernel_launch(void* const* d_in, const int* in_sizes, int n_in,
                              void* d_out, int out_size, void* d_ws, size_t ws_size,
                              hipStream_t stream)
{
  const float* x      = (const float*)d_in[0];
  const int*   adj    = (const int*)d_in[1];
  const float* weight = (const float*)d_in[2];
  const float* a      = (const float*)d_in[3];
  const float* bias   = (const float*)d_in[4];
  float* out = (float*)d_out;

  // workspace layout (all 16B aligned), ~12.3 MB total
  char* ws = (char*)d_ws;
  u16*   hT     = (u16*)ws;                                    // 4 MB
  float* Wh1    = (float*)(ws + (size_t)4 * 1024 * 1024);      // 64 KB
  float* Wh2    = Wh1 + BB * NN;                               // 64 KB
  float* S      = Wh2 + BB * NN;                               // 64 KB
  float* Sinv   = S + BB * NN;                                 // 64 KB (unused, keeps layout)
  unsigned int* m32 = (unsigned int*)(Sinv + BB * NN);         // 8 MB, [b][128][4096]
  float* norm2  = (float*)((char*)m32 + (size_t)BB * 128 * NN * 4);  // 2 KB

  hipMemsetAsync(S, 0, (size_t)BB * NN * sizeof(float), stream);
  hipMemsetAsync(norm2, 0, (size_t)BB * DOUT * sizeof(float), stream);

  k1_proj<<<dim3(NN / 32, BB), 256, 0, stream>>>(x, weight, a, hT, Wh1, Wh2);
  k2_fused<<<dim3(16, 32, BB), 256, 0, stream>>>(adj, Wh1, Wh2, S, m32);
  k3_attn<<<dim3(NN / 32, BB), 256, 0, stream>>>(m32, Wh1, Wh2, S, hT, out, norm2);
  k4b_scale<<<dim3((BB * NN * DOUT) / 256), 256, 0, stream>>>(out, norm2, bias);
}